// Round 2
// 1065.029 us; speedup vs baseline: 1.0110x; 1.0110x over previous
//
#include <hip/hip_runtime.h>
#include <cstdint>
#include <cstddef>

#define NTOK 8192
#define CDIM 1024
#define NEXP 8
#define HDIM 2730
#define HP   2816
#define NLIST 9          // 8 routed + 1 shared
#define MAXTILE 200      // 64 shared + <=136 routed m-tiles

typedef unsigned short u16;
typedef __attribute__((ext_vector_type(4))) float f32x4;
typedef __attribute__((ext_vector_type(8))) __bf16 bf16x8;
typedef __attribute__((ext_vector_type(4))) unsigned short u16x4;

// meta layout (ints): [0..8]=list counts, [16..24]=list offsets into perm,
// [30]=ntiles, [32..231]=tile->list, [288..487]=tile->m0, [576..583]=scatter cursor
#define M_CNT 0
#define M_OFF 16
#define M_NT  30
#define M_TL  32
#define M_TM  288
#define M_CUR 576

static __device__ __forceinline__ u16 f2bf(float f) {
  __bf16 h = (__bf16)f;
  return __builtin_bit_cast(u16, h);
}

// 16B-per-lane async global->LDS. LDS dest is wave-uniform base + lane*16.
static __device__ __forceinline__ void async_cp16(const void* gsrc, void* ldst) {
  auto g = reinterpret_cast<const __attribute__((address_space(1))) unsigned int*>(
      reinterpret_cast<uintptr_t>(gsrc));
  auto l = reinterpret_cast<__attribute__((address_space(3))) unsigned int*>(
      static_cast<unsigned int>(reinterpret_cast<uintptr_t>(ldst)));
  __builtin_amdgcn_global_load_lds(g, l, 16, 0, 0);
}

static __device__ __forceinline__ f32x4 mfma16(bf16x8 a, bf16x8 b, f32x4 c) {
  return __builtin_amdgcn_mfma_f32_16x16x32_bf16(a, b, c, 0, 0, 0);
}

// ---------------- x fp32 -> bf16 ----------------
__global__ void convert_x_kernel(const float* __restrict__ x, u16* __restrict__ xb) {
  size_t i = (size_t)blockIdx.x * blockDim.x + threadIdx.x;
  f32x4 v = ((const f32x4*)x)[i];
  u16x4 o;
  o.x = f2bf(v.x); o.y = f2bf(v.y); o.z = f2bf(v.z); o.w = f2bf(v.w);
  ((u16x4*)xb)[i] = o;
}

// ---------------- router: wave per token, no atomics ----------------
__global__ void router_kernel(const float* __restrict__ x, const float* __restrict__ gw,
                              int* __restrict__ idx_top, float* __restrict__ w_top,
                              float* __restrict__ probs,
                              int* __restrict__ perm_sh, float* __restrict__ scl_sh) {
  __shared__ float gws[NEXP][CDIM];   // transposed: lane stride 4B, conflict-free
  for (int i = threadIdx.x; i < CDIM * NEXP; i += 256) {
    int c = i >> 3, e = i & 7;
    gws[e][c] = gw[i];
  }
  __syncthreads();
  const int lane = threadIdx.x & 63;
  const int wave = threadIdx.x >> 6;
  const int t = blockIdx.x * 4 + wave;
  float acc[NEXP];
#pragma unroll
  for (int e = 0; e < NEXP; ++e) acc[e] = 0.f;
  const float* xr = x + (size_t)t * CDIM;
#pragma unroll
  for (int u = 0; u < CDIM / 64; ++u) {
    float xv = xr[lane + 64 * u];
#pragma unroll
    for (int e = 0; e < NEXP; ++e) acc[e] = fmaf(xv, gws[e][lane + 64 * u], acc[e]);
  }
#pragma unroll
  for (int e = 0; e < NEXP; ++e) {
    float v = acc[e];
#pragma unroll
    for (int s = 32; s > 0; s >>= 1) v += __shfl_xor(v, s, 64);
    acc[e] = v;
  }
  if (lane == 0) {
    float mx = acc[0];
#pragma unroll
    for (int e = 1; e < NEXP; ++e) mx = fmaxf(mx, acc[e]);
    float p[NEXP], s = 0.f;
#pragma unroll
    for (int e = 0; e < NEXP; ++e) { p[e] = __expf(acc[e] - mx); s += p[e]; }
    float inv = 1.f / s;
#pragma unroll
    for (int e = 0; e < NEXP; ++e) { p[e] *= inv; probs[t * NEXP + e] = p[e]; }
    int i1 = 0;
#pragma unroll
    for (int e = 1; e < NEXP; ++e) if (p[e] > p[i1]) i1 = e;
    int i2 = (i1 == 0) ? 1 : 0;
#pragma unroll
    for (int e = 0; e < NEXP; ++e)
      if (e != i1 && e != i2 && p[e] > p[i2]) i2 = e;
    float wsum = p[i1] + p[i2];
    idx_top[t * 2] = i1; idx_top[t * 2 + 1] = i2;
    w_top[t * 2] = p[i1] / wsum; w_top[t * 2 + 1] = p[i2] / wsum;
    perm_sh[t] = t; scl_sh[t] = 1.0f;
  }
}

// -------- single-block: counts, offsets, aux loss, tile table --------
__global__ void reduce_aux_kernel(const float* __restrict__ probs,
                                  const int* __restrict__ idx_top,
                                  int* __restrict__ meta, float* __restrict__ aux_out) {
  __shared__ float sP[NEXP];
  __shared__ int sC[NEXP];
  if (threadIdx.x < NEXP) { sP[threadIdx.x] = 0.f; sC[threadIdx.x] = 0; }
  __syncthreads();
  float sp[NEXP];
  int cnt[NEXP];
#pragma unroll
  for (int e = 0; e < NEXP; ++e) { sp[e] = 0.f; cnt[e] = 0; }
  for (int t = threadIdx.x; t < NTOK; t += 256) {
    const float* pr = probs + (size_t)t * NEXP;
    int i1 = idx_top[2 * t], i2 = idx_top[2 * t + 1];
#pragma unroll
    for (int e = 0; e < NEXP; ++e) {
      sp[e] += pr[e];
      cnt[e] += (i1 == e) + (i2 == e);
    }
  }
#pragma unroll
  for (int e = 0; e < NEXP; ++e) {
    float v = sp[e]; int c = cnt[e];
#pragma unroll
    for (int s = 32; s > 0; s >>= 1) { v += __shfl_xor(v, s, 64); c += __shfl_xor(c, s, 64); }
    if ((threadIdx.x & 63) == 0) { atomicAdd(&sP[e], v); atomicAdd(&sC[e], c); }
  }
  __syncthreads();
  if (threadIdx.x == 0) {
    int o = 0; float aux = 0.f;
    for (int e = 0; e < NEXP; ++e) {
      meta[M_CNT + e] = sC[e];
      meta[M_OFF + e] = o; o += sC[e];
      aux += ((float)sC[e] / (float)NTOK) * (sP[e] / (float)NTOK);
    }
    meta[M_CNT + 8] = NTOK;        // shared list
    meta[M_OFF + 8] = 2 * NTOK;
    aux_out[0] = (float)NEXP * aux;
    int nt = 0;
    for (int l = 0; l < NLIST; ++l) {
      int c = meta[M_CNT + l];
      for (int m0 = 0; m0 < c && nt < MAXTILE; m0 += 128) {
        meta[M_TL + nt] = l;
        meta[M_TM + nt] = m0;
        ++nt;
      }
    }
    meta[M_NT] = nt;
  }
}

// ------ scatter: block-aggregated cursor atomics ------
__global__ void scatter_kernel(const int* __restrict__ idx_top, const float* __restrict__ w_top,
                               int* __restrict__ meta,
                               int* __restrict__ perm, float* __restrict__ scl) {
  __shared__ int lcnt[NEXP], lbase[NEXP], lcur[NEXP];
  if (threadIdx.x < NEXP) { lcnt[threadIdx.x] = 0; lcur[threadIdx.x] = 0; }
  __syncthreads();
  int t = blockIdx.x * 256 + threadIdx.x;
  int e0 = idx_top[2 * t], e1 = idx_top[2 * t + 1];
  atomicAdd(&lcnt[e0], 1);
  atomicAdd(&lcnt[e1], 1);
  __syncthreads();
  if (threadIdx.x < NEXP)
    lbase[threadIdx.x] = atomicAdd(&meta[M_CUR + threadIdx.x], lcnt[threadIdx.x]);
  __syncthreads();
  int p0 = atomicAdd(&lcur[e0], 1);
  int o0 = meta[M_OFF + e0] + lbase[e0] + p0;
  perm[o0] = t; scl[o0] = w_top[2 * t];
  int p1 = atomicAdd(&lcur[e1], 1);
  int o1 = meta[M_OFF + e1] + lbase[e1] + p1;
  perm[o1] = t; scl[o1] = w_top[2 * t + 1];
}

// ---- all-weight fp32->bf16 transpose+pad: 27 matrices, one launch ----
// type A (w1/w2-like): src [1024][2730] -> dst [2816][1024]
// type B (w3-like):    src [2730][1024] -> dst [1024][2816]
__global__ void convt_all_kernel(const float* __restrict__ w1, const float* __restrict__ w2,
                                 const float* __restrict__ w3, const float* __restrict__ sw1,
                                 const float* __restrict__ sw2, const float* __restrict__ sw3,
                                 u16* __restrict__ w1b, u16* __restrict__ w2b,
                                 u16* __restrict__ w3b) {
  const int z = blockIdx.y;
  const float* src;
  u16* dst;
  int K, M, Kp;
  if (z < 8)       { src = w1 + (size_t)z * CDIM * HDIM;        dst = w1b + (size_t)z * HP * CDIM; K = CDIM; M = HDIM; Kp = CDIM; }
  else if (z < 16) { src = w2 + (size_t)(z - 8) * CDIM * HDIM;  dst = w2b + (size_t)(z - 8) * HP * CDIM; K = CDIM; M = HDIM; Kp = CDIM; }
  else if (z < 24) { src = w3 + (size_t)(z - 16) * HDIM * CDIM; dst = w3b + (size_t)(z - 16) * CDIM * HP; K = HDIM; M = CDIM; Kp = HP; }
  else if (z == 24){ src = sw1; dst = w1b + (size_t)8 * HP * CDIM; K = CDIM; M = HDIM; Kp = CDIM; }
  else if (z == 25){ src = sw2; dst = w2b + (size_t)8 * HP * CDIM; K = CDIM; M = HDIM; Kp = CDIM; }
  else             { src = sw3; dst = w3b + (size_t)8 * CDIM * HP; K = HDIM; M = CDIM; Kp = HP; }
  int t = blockIdx.x;
  int tk, tm;
  if (K == CDIM) { tk = t & 31; tm = t >> 5; }   // 32 k-tiles x 88 m-tiles
  else           { tk = t >> 5; tm = t & 31; }   // 88 k-tiles x 32 m-tiles
  __shared__ float tile[32][33];
  int sk = tk * 32, sm = tm * 32;
  int tx = threadIdx.x & 31, ty = threadIdx.x >> 5;
#pragma unroll
  for (int i = 0; i < 4; ++i) {
    int k = sk + ty + i * 8, m = sm + tx;
    tile[ty + i * 8][tx] = (k < K && m < M) ? src[(size_t)k * M + m] : 0.f;
  }
  __syncthreads();
#pragma unroll
  for (int i = 0; i < 4; ++i) {
    int m = sm + ty + i * 8, k = sk + tx;
    dst[(size_t)m * Kp + k] = f2bf(tile[tx][ty + i * 8]);
  }
}

// ------- merged fused dual GEMM + SwiGLU over all lists -------
// BM=128, BN=64, BK=32; 4 waves 2x2; dual accumulators (w1,w2 share A and B-addr).
// 2-phase double-buffer: prefetch tile t+1 BEFORE computing tile t; one sync per step.
// (__syncthreads = vmcnt(0)+lgkmcnt(0)+s_barrier, so no hand-rolled barriers needed.)
__global__ __launch_bounds__(256) void gemm_h_kernel(
    const u16* __restrict__ xb, const u16* __restrict__ w1b, const u16* __restrict__ w2b,
    u16* __restrict__ g, const int* __restrict__ perm, const int* __restrict__ meta) {
  const int bx = blockIdx.x;
  if (bx >= meta[M_NT]) return;
  const int l = meta[M_TL + bx];
  const int m0 = meta[M_TM + bx];
  const int Te = meta[M_CNT + l];
  const int lbase = meta[M_OFF + l];
  const int* pl = perm + lbase;
  const int n0 = blockIdx.y * 64;
  const u16* B1 = w1b + (size_t)l * HP * CDIM;
  const u16* B2 = w2b + (size_t)l * HP * CDIM;

  enum { ASZ = 128 * 32, BSZ = 64 * 32 };
  __shared__ __align__(16) u16 As[2 * ASZ];
  __shared__ __align__(16) u16 Bs1[2 * BSZ];
  __shared__ __align__(16) u16 Bs2[2 * BSZ];

  const int lane = threadIdx.x & 63;
  const int wave = threadIdx.x >> 6;
  const int wr = wave >> 1, wc = wave & 1;
  const int sr = lane >> 2;
  // XOR-swizzled source chunk: LDS slot (row, cs) holds global chunk cs^((row>>1)&3)
  const int scx = ((lane & 3) ^ ((sr >> 1) & 3)) * 8;

  int r0 = m0 + wave * 16 + sr;      if (r0 >= Te) r0 = Te - 1;
  int r1 = m0 + 64 + wave * 16 + sr; if (r1 >= Te) r1 = Te - 1;
  const u16* ga0 = xb + (size_t)pl[r0] * CDIM + scx;
  const u16* ga1 = xb + (size_t)pl[r1] * CDIM + scx;
  const u16* gb1 = B1 + (size_t)(n0 + wave * 16 + sr) * CDIM + scx;
  const u16* gb2 = B2 + (size_t)(n0 + wave * 16 + sr) * CDIM + scx;
  const int la0 = (wave * 16) * 32;          // per-wave LDS write offsets (in u16)
  const int la1 = (64 + wave * 16) * 32;
  const int lb  = (wave * 16) * 32;

  const int fr = lane & 15, fs = lane >> 4;
  const int fsx = (fs ^ ((fr >> 1) & 3)) * 8;   // swizzled read chunk
  int aoff[4], boff[2];
#pragma unroll
  for (int i = 0; i < 4; ++i) aoff[i] = (wr * 64 + i * 16 + fr) * 32 + fsx;
#pragma unroll
  for (int j = 0; j < 2; ++j) boff[j] = (wc * 32 + j * 16 + fr) * 32 + fsx;

  f32x4 acc1[4][2] = {};
  f32x4 acc2[4][2] = {};

  // prologue: stage K-tile 0 into buffer 0
  async_cp16(ga0, &As[la0]);
  async_cp16(ga1, &As[la1]);
  async_cp16(gb1, &Bs1[lb]);
  async_cp16(gb2, &Bs2[lb]);
  ga0 += 32; ga1 += 32; gb1 += 32; gb2 += 32;
  __syncthreads();

  int cur = 0;
#pragma unroll 1
  for (int k0 = 0; k0 < CDIM; k0 += 32) {
    const int nxt = cur ^ 1;
    if (k0 + 32 < CDIM) {            // issue NEXT tile's loads before computing this one
      async_cp16(ga0, &As[nxt * ASZ + la0]);
      async_cp16(ga1, &As[nxt * ASZ + la1]);
      async_cp16(gb1, &Bs1[nxt * BSZ + lb]);
      async_cp16(gb2, &Bs2[nxt * BSZ + lb]);
      ga0 += 32; ga1 += 32; gb1 += 32; gb2 += 32;
    }
    bf16x8 a[4], b1[2], b2[2];
#pragma unroll
    for (int i = 0; i < 4; ++i) a[i] = *(const bf16x8*)&As[cur * ASZ + aoff[i]];
#pragma unroll
    for (int j = 0; j < 2; ++j) {
      b1[j] = *(const bf16x8*)&Bs1[cur * BSZ + boff[j]];
      b2[j] = *(const bf16x8*)&Bs2[cur * BSZ + boff[j]];
    }
    __builtin_amdgcn_s_setprio(1);
#pragma unroll
    for (int i = 0; i < 4; ++i)
#pragma unroll
      for (int j = 0; j < 2; ++j) {
        acc1[i][j] = mfma16(a[i], b1[j], acc1[i][j]);
        acc2[i][j] = mfma16(a[i], b2[j], acc2[i][j]);
      }
    __builtin_amdgcn_s_setprio(0);
    __syncthreads();                 // drains prefetch (RAW) + guards buffer reuse (WAR)
    cur = nxt;
  }

  // epilogue: silu(h1)*h2 -> bf16 g rows (lbase+m0+m). C/D: col=lane&15, row=quad*4+reg.
#pragma unroll
  for (int i = 0; i < 4; ++i)
#pragma unroll
    for (int j = 0; j < 2; ++j)
#pragma unroll
      for (int r = 0; r < 4; ++r) {
        int m = wr * 64 + i * 16 + fs * 4 + r;
        if (m0 + m < Te) {
          int col = n0 + wc * 32 + j * 16 + fr;
          float h1 = acc1[i][j][r];
          float h2 = acc2[i][j][r];
          float gv = h1 / (1.f + __expf(-h1)) * h2;
          g[(size_t)(lbase + m0 + m) * HP + col] = f2bf(gv);
        }
      }
}

// ------- merged GEMM: y = g @ w3, atomically scatter s*y into out -------
// BM=128, BN=128, BK=32; 4 waves 2x2, each 64x64. Same 2-phase double-buffer.
__global__ __launch_bounds__(256) void gemm_out_kernel(
    const u16* __restrict__ g, const u16* __restrict__ w3b, float* __restrict__ out,
    const int* __restrict__ perm, const float* __restrict__ scl,
    const int* __restrict__ meta) {
  const int bx = blockIdx.x;
  if (bx >= meta[M_NT]) return;
  const int l = meta[M_TL + bx];
  const int m0 = meta[M_TM + bx];
  const int Te = meta[M_CNT + l];
  const int lbase = meta[M_OFF + l];
  const int n0 = blockIdx.y * 128;
  const u16* B3 = w3b + (size_t)l * CDIM * HP;

  enum { TSZ = 128 * 32 };
  __shared__ __align__(16) u16 As[2 * TSZ];
  __shared__ __align__(16) u16 Bs[2 * TSZ];

  const int lane = threadIdx.x & 63;
  const int wave = threadIdx.x >> 6;
  const int wr = wave >> 1, wc = wave & 1;
  const int sr = lane >> 2;
  const int scx = ((lane & 3) ^ ((sr >> 1) & 3)) * 8;

  // tail rows read garbage from the next list's region (in-bounds); results discarded.
  const u16* ga0 = g + (size_t)(lbase + m0 + wave * 16 + sr) * HP + scx;
  const u16* ga1 = g + (size_t)(lbase + m0 + 64 + wave * 16 + sr) * HP + scx;
  const u16* gb0 = B3 + (size_t)(n0 + wave * 16 + sr) * HP + scx;
  const u16* gb1 = B3 + (size_t)(n0 + 64 + wave * 16 + sr) * HP + scx;
  const int la0 = (wave * 16) * 32;
  const int la1 = (64 + wave * 16) * 32;
  const int lb0 = (wave * 16) * 32;
  const int lb1 = (64 + wave * 16) * 32;

  const int fr = lane & 15, fs = lane >> 4;
  const int fsx = (fs ^ ((fr >> 1) & 3)) * 8;
  int aoff[4], boff[4];
#pragma unroll
  for (int i = 0; i < 4; ++i) aoff[i] = (wr * 64 + i * 16 + fr) * 32 + fsx;
#pragma unroll
  for (int j = 0; j < 4; ++j) boff[j] = (wc * 64 + j * 16 + fr) * 32 + fsx;

  f32x4 acc[4][4] = {};

  // prologue: stage K-tile 0 into buffer 0
  async_cp16(ga0, &As[la0]);
  async_cp16(ga1, &As[la1]);
  async_cp16(gb0, &Bs[lb0]);
  async_cp16(gb1, &Bs[lb1]);
  ga0 += 32; ga1 += 32; gb0 += 32; gb1 += 32;
  __syncthreads();

  int cur = 0;
#pragma unroll 1
  for (int k0 = 0; k0 < HP; k0 += 32) {
    const int nxt = cur ^ 1;
    if (k0 + 32 < HP) {
      async_cp16(ga0, &As[nxt * TSZ + la0]);
      async_cp16(ga1, &As[nxt * TSZ + la1]);
      async_cp16(gb0, &Bs[nxt * TSZ + lb0]);
      async_cp16(gb1, &Bs[nxt * TSZ + lb1]);
      ga0 += 32; ga1 += 32; gb0 += 32; gb1 += 32;
    }
    bf16x8 a[4], b[4];
#pragma unroll
    for (int i = 0; i < 4; ++i) a[i] = *(const bf16x8*)&As[cur * TSZ + aoff[i]];
#pragma unroll
    for (int j = 0; j < 4; ++j) b[j] = *(const bf16x8*)&Bs[cur * TSZ + boff[j]];
    __builtin_amdgcn_s_setprio(1);
#pragma unroll
    for (int i = 0; i < 4; ++i)
#pragma unroll
      for (int j = 0; j < 4; ++j)
        acc[i][j] = mfma16(a[i], b[j], acc[i][j]);
    __builtin_amdgcn_s_setprio(0);
    __syncthreads();
    cur = nxt;
  }

#pragma unroll
  for (int i = 0; i < 4; ++i) {
#pragma unroll
    for (int r = 0; r < 4; ++r) {
      int m = wr * 64 + i * 16 + fs * 4 + r;
      int grow = m0 + m;
      if (grow < Te) {
        int slot = lbase + grow;
        int tok = perm[slot];
        float s = scl[slot];
#pragma unroll
        for (int j = 0; j < 4; ++j) {
          int col = n0 + wc * 64 + j * 16 + fr;
          atomicAdd(&out[(size_t)tok * CDIM + col], s * acc[i][j][r]);
        }
      }
    }
  }
}

extern "C" void kernel_launch(void* const* d_in, const int* in_sizes, int n_in,
                              void* d_out, int out_size, void* d_ws, size_t ws_size,
                              hipStream_t stream) {
  (void)in_sizes; (void)n_in; (void)out_size; (void)ws_size;
  const float* x   = (const float*)d_in[0];
  const float* gw  = (const float*)d_in[1];
  const float* w1  = (const float*)d_in[2];
  const float* w2  = (const float*)d_in[3];
  const float* w3  = (const float*)d_in[4];
  const float* sw1 = (const float*)d_in[5];
  const float* sw2 = (const float*)d_in[6];
  const float* sw3 = (const float*)d_in[7];
  float* out = (float*)d_out;

  char* p = (char*)d_ws;
  auto alloc = [&](size_t b) { char* r = p; p += (b + 255) & ~(size_t)255; return r; };
  u16*   xb      = (u16*)alloc((size_t)NTOK * CDIM * 2);
  u16*   w1b     = (u16*)alloc((size_t)NLIST * HP * CDIM * 2);
  u16*   w2b     = (u16*)alloc((size_t)NLIST * HP * CDIM * 2);
  u16*   w3b     = (u16*)alloc((size_t)NLIST * CDIM * HP * 2);
  u16*   gbuf    = (u16*)alloc((size_t)3 * NTOK * HP * 2);
  int*   idx_top = (int*)alloc((size_t)NTOK * 2 * 4);
  float* w_top   = (float*)alloc((size_t)NTOK * 2 * 4);
  float* probs   = (float*)alloc((size_t)NTOK * NEXP * 4);
  int*   perm    = (int*)alloc((size_t)NTOK * 3 * 4);
  float* scl     = (float*)alloc((size_t)NTOK * 3 * 4);
  int*   meta    = (int*)alloc(4096);

  hipMemsetAsync(out, 0, ((size_t)NTOK * CDIM + 1) * 4, stream);
  hipMemsetAsync(meta, 0, 4096, stream);
  convert_x_kernel<<<NTOK * CDIM / 4 / 256, 256, 0, stream>>>(x, xb);
  router_kernel<<<NTOK / 4, 256, 0, stream>>>(x, gw, idx_top, w_top, probs,
                                              perm + 2 * NTOK, scl + 2 * NTOK);
  reduce_aux_kernel<<<1, 256, 0, stream>>>(probs, idx_top, meta,
                                           out + (size_t)NTOK * CDIM);
  scatter_kernel<<<NTOK / 256, 256, 0, stream>>>(idx_top, w_top, meta, perm, scl);
  convt_all_kernel<<<dim3(2816, 27), 256, 0, stream>>>(w1, w2, w3, sw1, sw2, sw3,
                                                       w1b, w2b, w3b);
  gemm_h_kernel<<<dim3(MAXTILE, HP / 64), 256, 0, stream>>>(
      xb, w1b, w2b, gbuf, perm, meta);
  gemm_out_kernel<<<dim3(MAXTILE, CDIM / 128), 256, 0, stream>>>(
      gbuf, w3b, out, perm, scl, meta);
}